// Round 3
// baseline (73.181 us; speedup 1.0000x reference)
//
#include <hip/hip_runtime.h>

#define DFEAT 64
#define MAXK 256   // LDS row-staging cap; P(row degree > 256) ~ 0 for 131072 random
                   // edges over 8192 rows (Poisson lambda=16); exact global
                   // fallback handles p>=MAXK anyway.

// ---------------------------------------------------------------------------
// K1: zero the two counter arrays (cnt, deg). 64 KB total.
// ---------------------------------------------------------------------------
__global__ void zero_kernel(int* __restrict__ cnt, int* __restrict__ deg, int nN) {
    int i = blockIdx.x * blockDim.x + threadIdx.x;
    if (i < nN) { cnt[i] = 0; deg[i] = 0; }
}

// ---------------------------------------------------------------------------
// K2: row counts. cnt[e0]++ per edge (int atomics, avg 16/counter).
// ---------------------------------------------------------------------------
__global__ void count_kernel(const int* __restrict__ ei, int* __restrict__ cnt, int nE) {
    int e = blockIdx.x * blockDim.x + threadIdx.x;
    if (e >= nE) return;
    atomicAdd(&cnt[ei[e]], 1);
}

// ---------------------------------------------------------------------------
// K3: exclusive scan of cnt -> off (and cur=off cursor copy). nN=8192 with a
// single 1024-thread block: 8/thread serial + Hillis-Steele on 1024 partials.
// ---------------------------------------------------------------------------
__global__ void scan_kernel(const int* __restrict__ cnt, int* __restrict__ off,
                            int* __restrict__ cur, int nN) {
    __shared__ int partial[1024];
    int tid = threadIdx.x;
    int base = tid * 8;
    int loc[8];
    int s = 0;
    for (int u = 0; u < 8; ++u) { loc[u] = s; s += cnt[base + u]; }
    partial[tid] = s;
    __syncthreads();
    for (int d = 1; d < 1024; d <<= 1) {
        int v = partial[tid];
        int w = (tid >= d) ? partial[tid - d] : 0;
        __syncthreads();
        partial[tid] = v + w;
        __syncthreads();
    }
    int rowbase = (tid == 0) ? 0 : partial[tid - 1];
    for (int u = 0; u < 8; ++u) {
        int o = rowbase + loc[u];
        off[base + u] = o;
        cur[base + u] = o;
    }
    if (tid == 1023) off[nN] = partial[1023];
}

// ---------------------------------------------------------------------------
// K4: fill CSR slots. slots[cur[e0]++] = e1.
// ---------------------------------------------------------------------------
__global__ void fill_kernel(const int* __restrict__ ei, int* __restrict__ cur,
                            int* __restrict__ slots, int nE) {
    int e = blockIdx.x * blockDim.x + threadIdx.x;
    if (e >= nE) return;
    int pos = atomicAdd(&cur[ei[e]], 1);
    slots[pos] = ei[nE + e];
}

// ---------------------------------------------------------------------------
// K5: per-row dedupe (set semantics!) + column degree. One wave per row;
// row staged in LDS; slot p is a duplicate iff an earlier slot holds the
// same j. Unique slots: uflags=1 and deg[j]++ (int atomic).
// ---------------------------------------------------------------------------
__global__ void dedupe_kernel(const int* __restrict__ off, const int* __restrict__ slots,
                              unsigned char* __restrict__ uflags, int* __restrict__ deg) {
    __shared__ int row[4][MAXK];
    int wid = threadIdx.x >> 6, lane = threadIdx.x & 63;
    int i = blockIdx.x * 4 + wid;
    int base = off[i];
    int k = off[i + 1] - base;
    int kc = k < MAXK ? k : MAXK;
    for (int p = lane; p < kc; p += 64) row[wid][p] = slots[base + p];
    __syncthreads();
    for (int p = lane; p < k; p += 64) {
        int v = (p < MAXK) ? row[wid][p] : slots[base + p];
        bool dup = false;
        for (int m = 0; m < p; ++m) {
            int u = (m < MAXK) ? row[wid][m] : slots[base + m];
            if (u == v) { dup = true; break; }
        }
        uflags[base + p] = dup ? 0 : 1;
        if (!dup) atomicAdd(&deg[v], 1);
    }
}

// ---------------------------------------------------------------------------
// K6: dvec[i] = rsqrt(deg[i]+1)  (+1 = self-loop from +I);  y = dvec*x.
// float4-vectorized.
// ---------------------------------------------------------------------------
__global__ void scale_kernel(const float* __restrict__ x, const int* __restrict__ deg,
                             float* __restrict__ dvec, float* __restrict__ y, int total4) {
    int i = blockIdx.x * blockDim.x + threadIdx.x;
    if (i >= total4) return;
    int node = i >> 4;
    float dv = rsqrtf((float)(deg[node] + 1));
    if ((i & 15) == 0) dvec[node] = dv;
    float4 v = ((const float4*)x)[i];
    v.x *= dv; v.y *= dv; v.z *= dv; v.w *= dv;
    ((float4*)y)[i] = v;
}

// ---------------------------------------------------------------------------
// K7: gather + normalize + fused linear. One wave per row i:
//   acc[lane] = y[i][lane] + sum over unique neighbors j of y[j][lane]
//   h = dvec[i]*acc;  out[i][o] = b[o] + sum_k h[k]*W[o][k]
// Neighbor reads are wave-coalesced 256B from L2-resident y (2 MB).
// ---------------------------------------------------------------------------
__global__ void gather_kernel(const int* __restrict__ off, const int* __restrict__ slots,
                              const unsigned char* __restrict__ uflags,
                              const float* __restrict__ y, const float* __restrict__ dvec,
                              const float* __restrict__ W, const float* __restrict__ b,
                              float* __restrict__ out) {
    __shared__ float hsm[4][DFEAT];
    __shared__ float Wt[DFEAT][DFEAT + 1];
    int tid = threadIdx.x;
    for (int idx = tid; idx < DFEAT * DFEAT; idx += 256) {
        int o = idx >> 6, kk = idx & 63;
        Wt[kk][o] = W[idx];
    }
    int wid = tid >> 6, lane = tid & 63;
    int i = blockIdx.x * 4 + wid;
    int base = off[i];
    int k = off[i + 1] - base;
    float acc = y[(size_t)i * DFEAT + lane];          // self (+I)
    for (int p = 0; p < k; ++p) {
        int j = slots[base + p];                       // wave-uniform load
        if (uflags[base + p])                          // wave-uniform branch
            acc += y[(size_t)j * DFEAT + lane];        // coalesced 256B
    }
    float h = dvec[i] * acc;
    hsm[wid][lane] = h;
    __syncthreads();
    float r = b[lane];
#pragma unroll
    for (int kk = 0; kk < DFEAT; ++kk)
        r = fmaf(hsm[wid][kk], Wt[kk][lane], r);
    out[(size_t)i * DFEAT + lane] = r;
}

// ---------------------------------------------------------------------------
extern "C" void kernel_launch(void* const* d_in, const int* in_sizes, int n_in,
                              void* d_out, int out_size, void* d_ws, size_t ws_size,
                              hipStream_t stream) {
    const float* x  = (const float*)d_in[0];
    const int*   ei = (const int*)d_in[1];
    const float* W  = (const float*)d_in[2];
    const float* b  = (const float*)d_in[3];
    float* out = (float*)d_out;

    int nN = in_sizes[0] / DFEAT;   // 8192
    int nE = in_sizes[1] / 2;       // 131072

    // Workspace layout (all re-initialized every call; ws is NOT re-poisoned
    // between replays so nothing may carry state):
    char* ws = (char*)d_ws;
    size_t o = 0;
    int* cnt   = (int*)(ws + o); o += (size_t)nN * 4;
    int* deg   = (int*)(ws + o); o += (size_t)nN * 4;
    int* off   = (int*)(ws + o); o += (size_t)(nN + 1) * 4;
    o = (o + 255) & ~(size_t)255;
    int* cur   = (int*)(ws + o); o += (size_t)nN * 4;
    int* slots = (int*)(ws + o); o += (size_t)nE * 4;
    unsigned char* uflags = (unsigned char*)(ws + o); o += (size_t)nE;
    o = (o + 255) & ~(size_t)255;
    float* dvec = (float*)(ws + o); o += (size_t)nN * 4;
    float* y    = (float*)(ws + o); o += (size_t)nN * DFEAT * 4;

    zero_kernel<<<(nN + 255) / 256, 256, 0, stream>>>(cnt, deg, nN);
    count_kernel<<<(nE + 255) / 256, 256, 0, stream>>>(ei, cnt, nE);
    scan_kernel<<<1, 1024, 0, stream>>>(cnt, off, cur, nN);
    fill_kernel<<<(nE + 255) / 256, 256, 0, stream>>>(ei, cur, slots, nE);
    dedupe_kernel<<<nN / 4, 256, 0, stream>>>(off, slots, uflags, deg);
    int total4 = nN * DFEAT / 4;
    scale_kernel<<<(total4 + 255) / 256, 256, 0, stream>>>(x, deg, dvec, y, total4);
    gather_kernel<<<nN / 4, 256, 0, stream>>>(off, slots, uflags, y, dvec, W, b, out);
}